// Round 17
// baseline (191.347 us; speedup 1.0000x reference)
//
#include <hip/hip_runtime.h>

// Fused LN -> QKV -> MHA -> out-proj for [4,2048,1024], 16 heads, hd=64.
// GEMMs: 8-phase-style 256x128 tile, BK=64, 3 LDS buffers (144KB), counted
// vmcnt(6) once per K-tile (never 0 in steady state), 2 phases x 16 MFMA per
// tile with dual barriers (T3+T4+T5). Attention: 8-wave paired-KV (frozen).

typedef _Float16 h16;
typedef __attribute__((ext_vector_type(8))) _Float16 h16x8;
typedef __attribute__((ext_vector_type(4))) _Float16 h16x4;
typedef __attribute__((ext_vector_type(2))) _Float16 h16x2;
typedef __attribute__((ext_vector_type(4))) float f32x4;

#define B_ 4
#define S_ 2048
#define D_ 1024

static __device__ __forceinline__ void async16(void* lds, const void* g) {
  __builtin_amdgcn_global_load_lds((const __attribute__((address_space(1))) void*)g,
                                   (__attribute__((address_space(3))) void*)lds,
                                   16, 0, 0);
}

static __device__ __forceinline__ float ex2(float x) {
  float r;
  asm("v_exp_f32 %0, %1" : "=v"(r) : "v"(x));
  return r;
}

static __device__ __forceinline__ h16x2 pk2(float a, float b) {
  h16x2 r;
  asm("v_cvt_pkrtz_f16_f32 %0, %1, %2" : "=v"(r) : "v"(a), "v"(b));
  return r;
}

union U8 { h16x8 v; h16x2 h[4]; };

// ---------------- prep: LN (blocks 0..8191) + weight cvt (rest) -------------
__global__ __launch_bounds__(256) void prep_k(const float* __restrict__ x,
                                              const float* __restrict__ g,
                                              const float* __restrict__ be,
                                              h16* __restrict__ xn,
                                              const float* __restrict__ wq,
                                              h16* __restrict__ wqkv,
                                              const float* __restrict__ wo,
                                              h16* __restrict__ wout) {
  const int bid = blockIdx.x;
  const int tid = threadIdx.x;
  if (bid < 8192) {
    const int row = bid;
    const float4 v = ((const float4*)(x + (size_t)row * D_))[tid];
    float s = v.x + v.y + v.z + v.w;
    float s2 = v.x * v.x + v.y * v.y + v.z * v.z + v.w * v.w;
#pragma unroll
    for (int msk = 1; msk < 64; msk <<= 1) {
      s += __shfl_xor(s, msk);
      s2 += __shfl_xor(s2, msk);
    }
    __shared__ float red[8];
    const int wv = tid >> 6, ln = tid & 63;
    if (ln == 0) { red[wv] = s; red[wv + 4] = s2; }
    __syncthreads();
    s = red[0] + red[1] + red[2] + red[3];
    s2 = red[4] + red[5] + red[6] + red[7];
    const float mu = s * (1.f / D_);
    const float rs = rsqrtf(s2 * (1.f / D_) - mu * mu + 1e-5f);
    const float4 gv = ((const float4*)g)[tid];
    const float4 bv = ((const float4*)be)[tid];
    h16x4 o;
    o[0] = (h16)((v.x - mu) * rs * gv.x + bv.x);
    o[1] = (h16)((v.y - mu) * rs * gv.y + bv.y);
    o[2] = (h16)((v.z - mu) * rs * gv.z + bv.z);
    o[3] = (h16)((v.w - mu) * rs * gv.w + bv.w);
    *(h16x4*)(xn + (size_t)row * D_ + tid * 4) = o;
  } else if (bid < 8192 + 3072) {
    const int i = (bid - 8192) * 256 + tid;
    const float4 v = ((const float4*)wq)[i];
    h16x4 r;
    r[0] = (h16)v.x; r[1] = (h16)v.y; r[2] = (h16)v.z; r[3] = (h16)v.w;
    *(h16x4*)(wqkv + (size_t)i * 4) = r;
  } else {
    const int i = (bid - 8192 - 3072) * 256 + tid;
    const float4 v = ((const float4*)wo)[i];
    h16x4 r;
    r[0] = (h16)v.x; r[1] = (h16)v.y; r[2] = (h16)v.z; r[3] = (h16)v.w;
    *(h16x4*)(wout + (size_t)i * 4) = r;
  }
}

// ---------------- V transpose: qkv V-region -> vT[bh*64+d][2048 kv] ----------
__global__ __launch_bounds__(256) void vt_k(const h16* __restrict__ qkv,
                                            h16* __restrict__ vT) {
  __shared__ h16 T[64 * 72];
  const int tid = threadIdx.x;
  const int kv0 = blockIdx.x * 64;
  const int bh = blockIdx.y;
  const int b = bh >> 4, h = bh & 15;
#pragma unroll
  for (int it = 0; it < 2; ++it) {
    const int s = tid + it * 256;
    const int kv = s >> 3, sl = s & 7;
    const int wsl = sl ^ ((kv >> 3) & 7);
    const h16x8 v = *(const h16x8*)(qkv + (size_t)(b * S_ + kv0 + kv) * 3072 + 2048 + h * 64 + sl * 8);
    *(h16x8*)(T + kv * 72 + wsl * 8) = v;
  }
  __syncthreads();
#pragma unroll
  for (int it = 0; it < 2; ++it) {
    const int s = tid + it * 256;
    const int d = s >> 3, sl = s & 7;
    h16x8 v;
#pragma unroll
    for (int j = 0; j < 8; ++j) {
      const int kv = sl * 8 + j;
      v[j] = T[kv * 72 + (((d >> 3) ^ sl) & 7) * 8 + (d & 7)];
    }
    *(h16x8*)(vT + (size_t)(bh * 64 + d) * 2048 + kv0 + sl * 8) = v;
  }
}

// ---------------- GEMM8: C[M,N]=A[M,K]*B[N,K]^T, 256x128, BK=64, 8-phase ----
// 512 thr = 8 waves (2M x 4N); per-wave output 128x32 (acc[8][2]).
// 3 LDS buffers, prefetch distance 2 tiles. Per K-tile: 2 phases of
// {10 ds_read + stage-issue -> BAR -> lgkm(0) -> 16 MFMA -> BAR};
// vmcnt(6) once per tile (A(t+2)x4 + B(t+2)x2 stay in flight).
__global__ __launch_bounds__(512) void gemm8(const h16* __restrict__ A, int lda,
                                             const h16* __restrict__ Bm,
                                             float* __restrict__ Cf,
                                             h16* __restrict__ Ch,
                                             int M, int N, int K,
                                             int scale_cols, float scale) {
  __shared__ __align__(16) h16 As[3][256 * 64];
  __shared__ __align__(16) h16 Bs[3][128 * 64];
  const int tid = threadIdx.x;
  const int wv = tid >> 6, ln = tid & 63;
  const int l15 = ln & 15, l4 = ln >> 4;
  const int row0 = blockIdx.x * 256, col0 = blockIdx.y * 128;
  const int wr = (wv >> 2) * 128, wc = (wv & 3) * 32;
  f32x4 acc[8][2] = {};

  // staging: wave wv writes 1KB linear chunks; lane covers row wv*8+(ln>>3),
  // slot ln&7, holding global slot (ln&7)^(row&7) (pre-swizzled source).
  const int srow = wv * 8 + (ln >> 3);
  const int sslot = (ln & 7) ^ ((ln >> 3) & 7);
  const h16* ag = A + (size_t)(row0 + srow) * lda + sslot * 8;
  const h16* bg = Bm + (size_t)(col0 + srow) * K + sslot * 8;

#define GLA(BUF, T) do {                                                     \
    const size_t k_ = (size_t)(T) * 64;                                      \
    async16((char*)As[BUF] + wv * 1024,          ag + k_);                   \
    async16((char*)As[BUF] + 8192 + wv * 1024,   ag + (size_t)64 * lda + k_);\
    async16((char*)As[BUF] + 16384 + wv * 1024,  ag + (size_t)128 * lda + k_);\
    async16((char*)As[BUF] + 24576 + wv * 1024,  ag + (size_t)192 * lda + k_);\
  } while (0)

#define GLB(BUF, T) do {                                                     \
    const size_t k_ = (size_t)(T) * 64;                                      \
    async16((char*)Bs[BUF] + wv * 1024,          bg + k_);                   \
    async16((char*)Bs[BUF] + 8192 + wv * 1024,   bg + (size_t)64 * K + k_);  \
  } while (0)

#define RDFRAGS(BUF, KS, AF, BF) do {                                        \
    const h16* Ab_ = As[BUF];                                                \
    const h16* Bb_ = Bs[BUF];                                                \
    _Pragma("unroll")                                                        \
    for (int i = 0; i < 8; ++i)                                              \
      AF[i] = *(const h16x8*)(Ab_ + (wr + i * 16 + l15) * 64 +               \
                              ((((KS) * 4 + l4) ^ (l15 & 7)) * 8));          \
    _Pragma("unroll")                                                        \
    for (int j = 0; j < 2; ++j)                                              \
      BF[j] = *(const h16x8*)(Bb_ + (wc + j * 16 + l15) * 64 +               \
                              ((((KS) * 4 + l4) ^ (l15 & 7)) * 8));          \
  } while (0)

#define MFMAS(AF, BF) do {                                                   \
    __builtin_amdgcn_s_setprio(1);                                           \
    _Pragma("unroll")                                                        \
    for (int i = 0; i < 8; ++i)                                              \
      _Pragma("unroll")                                                      \
      for (int j = 0; j < 2; ++j)                                            \
        acc[i][j] = __builtin_amdgcn_mfma_f32_16x16x32_f16(AF[i], BF[j], acc[i][j], 0, 0, 0); \
    __builtin_amdgcn_s_setprio(0);                                           \
  } while (0)

#define SB() __builtin_amdgcn_sched_barrier(0)
#define BAR() do { SB(); __builtin_amdgcn_s_barrier(); SB(); } while (0)

// BODY(T, BUF): two phases for K-tile T residing in buffer BUF = T%3.
// P0: ds_read ks0 || issue A(T+2); P1: ds_read ks1 || issue B(T+2) + vmcnt.
#define GBODY(T, BUF, VM) do {                                               \
    {                                                                        \
      h16x8 af[8], bf[2];                                                    \
      RDFRAGS(BUF, 0, af, bf);                                               \
      if ((T) + 2 < 16) GLA(((BUF) + 2) % 3, (T) + 2);                       \
      BAR();                                                                 \
      asm volatile("s_waitcnt lgkmcnt(0)" ::: "memory"); SB();               \
      MFMAS(af, bf);                                                         \
      BAR();                                                                 \
    }                                                                        \
    {                                                                        \
      h16x8 af[8], bf[2];                                                    \
      RDFRAGS(BUF, 1, af, bf);                                               \
      if ((T) + 2 < 16) GLB(((BUF) + 2) % 3, (T) + 2);                       \
      asm volatile("s_waitcnt vmcnt(" #VM ")" ::: "memory"); SB();           \
      BAR();                                                                 \
      asm volatile("s_waitcnt lgkmcnt(0)" ::: "memory"); SB();               \
      MFMAS(af, bf);                                                         \
      BAR();                                                                 \
    }                                                                        \
  } while (0)

  // prologue: tiles 0,1 fully staged; tile 0 certified, tile 1 in flight
  GLA(0, 0); GLB(0, 0);
  GLA(1, 1); GLB(1, 1);
  asm volatile("s_waitcnt vmcnt(6)" ::: "memory"); SB();
  BAR();

  // K = 1024 -> 16 tiles; unroll 3 for static buffer indices
  for (int t3 = 0; t3 < 12; t3 += 3) {
    GBODY(t3 + 0, 0, 6);
    GBODY(t3 + 1, 1, 6);
    GBODY(t3 + 2, 2, 6);
  }
  GBODY(12, 0, 6);
  GBODY(13, 1, 6);
  GBODY(14, 2, 0);
  GBODY(15, 0, 0);

  // epilogue
#pragma unroll
  for (int i = 0; i < 8; ++i)
#pragma unroll
    for (int j = 0; j < 2; ++j) {
      const int col = col0 + wc + j * 16 + l15;
      const float sc = (col < scale_cols) ? scale : 1.f;
#pragma unroll
      for (int r = 0; r < 4; ++r) {
        const int row = row0 + wr + i * 16 + l4 * 4 + r;
        const float vv = acc[i][j][r] * sc;
        if (Ch) Ch[(size_t)row * N + col] = (h16)vv;
        else    Cf[(size_t)row * N + col] = vv;
      }
    }
#undef GLA
#undef GLB
#undef RDFRAGS
#undef MFMAS
#undef SB
#undef BAR
#undef GBODY
}

// ---------------- Flash attention (8-wave, paired KV tiles) ----------------
__global__ __launch_bounds__(512) void attn_k(h16* __restrict__ qkv,
                                              const h16* __restrict__ vT) {
  __shared__ __align__(16) h16 Ks[2][2][64 * 64];
  __shared__ __align__(16) h16 Vs[2][2][64 * 64];
  const int tid = threadIdx.x;
  const int wv = tid >> 6, ln = tid & 63;
  const int l15 = ln & 15, l4 = ln >> 4;
  const int bh = blockIdx.x;
  const int b = bh >> 4, h = bh & 15;
  const size_t rb = (size_t)b * S_;
  const int qb = blockIdx.y * 256 + wv * 32;

  h16x8 qf[2][2];
#pragma unroll
  for (int qb2 = 0; qb2 < 2; ++qb2)
#pragma unroll
    for (int ks = 0; ks < 2; ++ks)
      qf[qb2][ks] = *(const h16x8*)(qkv + (rb + qb + qb2 * 16 + l15) * 3072 + h * 64 + ks * 32 + l4 * 8);

  f32x4 o[2][4] = {};
  f32x4 lsum[2] = {};
  h16x8 ones8;
#pragma unroll
  for (int j = 0; j < 8; ++j) ones8[j] = (h16)1.f;

  const int srow = wv * 8 + (ln >> 3);
  const int ssl = (ln & 7) ^ (srow & 7);
  const h16* kgb = qkv + (rb + srow) * 3072 + 1024 + h * 64 + ssl * 8;

  const int vd = tid >> 3;
  const int s8 = tid & 7;
  const int vks = s8 >> 2, vb0b = s8 & 1, vhi = (s8 >> 1) & 1;
  const int vd7 = vd & 7;
  const h16* vgb = vT + (size_t)(bh * 64 + vd) * 2048 + s8 * 8;
  const int dstA = vd * 64 + (((vks * 4 + (vb0b * 2)) ^ vd7) * 8) + vhi * 4;
  const int dstB = vd * 64 + (((vks * 4 + (vb0b * 2 + 1)) ^ vd7) * 8) + vhi * 4;

  int jro[4], slx[2];
#pragma unroll
  for (int j = 0; j < 4; ++j) jro[j] = (j * 16 + l15) * 64;
#pragma unroll
  for (int ks = 0; ks < 2; ++ks) slx[ks] = ((ks * 4 + l4) ^ (l15 & 7)) * 8;

  h16x8 va0, va1, vb0, vb1;

#define ISSUEK2(BUF, P) do {                                                 \
    const h16* kg_ = kgb + (size_t)(2 * (P)) * 64 * 3072;                    \
    async16((char*)Ks[BUF][0] + wv * 1024, kg_);                             \
    async16((char*)Ks[BUF][1] + wv * 1024, kg_ + (size_t)64 * 3072);         \
  } while (0)

#define VLOAD2(P, R0, R1) do {                                               \
    R0 = *(const h16x8*)(vgb + (2 * (P)) * 64);                              \
    R1 = *(const h16x8*)(vgb + (2 * (P) + 1) * 64);                          \
  } while (0)

#define VSTOREM2(BUF, S0, S1) do {                                           \
    *(h16x4*)(Vs[BUF][0] + dstA) = __builtin_shufflevector(S0, S0, 0, 1, 2, 3); \
    *(h16x4*)(Vs[BUF][0] + dstB) = __builtin_shufflevector(S0, S0, 4, 5, 6, 7); \
    *(h16x4*)(Vs[BUF][1] + dstA) = __builtin_shufflevector(S1, S1, 0, 1, 2, 3); \
    *(h16x4*)(Vs[BUF][1] + dstB) = __builtin_shufflevector(S1, S1, 4, 5, 6, 7); \
  } while (0)

#define COMPUTE1(Kb_, Vb_) do {                                              \
    f32x4 st[2][4] = {};                                                     \
    __builtin_amdgcn_s_setprio(1);                                           \
    _Pragma("unroll")                                                        \
    for (int ks = 0; ks < 2; ++ks) {                                         \
      h16x8 kb[4];                                                           \
      _Pragma("unroll")                                                      \
      for (int jb = 0; jb < 4; ++jb)                                         \
        kb[jb] = *(const h16x8*)(Kb_ + jro[jb] + slx[ks]);                   \
      _Pragma("unroll")                                                      \
      for (int qq = 0; qq < 2; ++qq)                                         \
        _Pragma("unroll")                                                    \
        for (int jb = 0; jb < 4; ++jb)                                       \
          st[qq][jb] = __builtin_amdgcn_mfma_f32_16x16x32_f16(kb[jb], qf[qq][ks], st[qq][jb], 0, 0, 0); \
    }                                                                        \
    __builtin_amdgcn_s_setprio(0);                                           \
    h16x8 vfr[2][4];                                                         \
    _Pragma("unroll")                                                        \
    for (int ks = 0; ks < 2; ++ks)                                           \
      _Pragma("unroll")                                                      \
      for (int jd = 0; jd < 4; ++jd)                                         \
        vfr[ks][jd] = *(const h16x8*)(Vb_ + jro[jd] + slx[ks]);              \
    _Pragma("unroll")                                                        \
    for (int qq = 0; qq < 2; ++qq) {                                         \
      h16x8 pa[2];                                                           \
      _Pragma("unroll")                                                      \
      for (int ks = 0; ks < 2; ++ks) {                                       \
        U8 u_;                                                               \
        u_.h[0] = pk2(ex2(st[qq][2 * ks][0]), ex2(st[qq][2 * ks][1]));       \
        u_.h[1] = pk2(ex2(st[qq][2 * ks][2]), ex2(st[qq][2 * ks][3]));       \
        u_.h[2] = pk2(ex2(st[qq][2 * ks + 1][0]), ex2(st[qq][2 * ks + 1][1])); \
        u_.h[3] = pk2(ex2(st[qq][2 * ks + 1][2]), ex2(st[qq][2 * ks + 1][3])); \
        pa[ks] = u_.v;                                                       \
      }                                                                      \
      __builtin_amdgcn_s_setprio(1);                                         \
      _Pragma("unroll")                                                      \
      for (int jd = 0; jd < 4; ++jd)                                         \
        o[qq][jd] = __builtin_amdgcn_mfma_f32_16x16x32_f16(pa[0], vfr[0][jd], o[qq][jd], 0, 0, 0); \
      lsum[qq] = __builtin_amdgcn_mfma_f32_16x16x32_f16(pa[0], ones8, lsum[qq], 0, 0, 0); \
      _Pragma("unroll")                                                      \
      for (int jd = 0; jd < 4; ++jd)                                         \
        o[qq][jd] = __builtin_amdgcn_mfma_f32_16x16x32_f16(pa[1], vfr[1][jd], o[qq][jd], 0, 0, 0); \
      lsum[qq] = __builtin_amdgcn_mfma_f32_16x16x32_f16(pa[1], ones8, lsum[qq], 0, 0, 0); \
      __builtin_amdgcn_s_setprio(0);                                         \
    }                                                                        \
  } while (0)

#define COMPUTE2(BUF) do {                                                   \
    COMPUTE1((Ks[BUF][0]), (Vs[BUF][0]));                                    \
    COMPUTE1((Ks[BUF][1]), (Vs[BUF][1]));                                    \
  } while (0)

#define ENDBAR(VM) do {                                                      \
    asm volatile("s_waitcnt vmcnt(" #VM ") lgkmcnt(0)" ::: "memory");        \
    __builtin_amdgcn_sched_barrier(0);                                       \
    __builtin_amdgcn_s_barrier();                                            \
  } while (0)

#define BODYP(P, VM, VS0, VS1, VL0, VL1) do {                                \
    VSTOREM2(((P) + 1) & 1, VS0, VS1);                                       \
    ISSUEK2(((P) + 1) & 1, (P) + 1);                                         \
    if ((P) + 2 < 16) VLOAD2((P) + 2, VL0, VL1);                             \
    COMPUTE2((P) & 1);                                                       \
    ENDBAR(VM);                                                              \
  } while (0)

  ISSUEK2(0, 0);
  VLOAD2(0, va0, va1);
  VSTOREM2(0, va0, va1);
  VLOAD2(1, vb0, vb1);
  ENDBAR(2);

  for (int p = 0; p < 14; p += 2) {
    BODYP(p + 0, 2, vb0, vb1, va0, va1);
    BODYP(p + 1, 2, va0, va1, vb0, vb1);
  }
  BODYP(14, 0, vb0, vb1, va0, va1);
  COMPUTE2(1);

#pragma unroll
  for (int qb2 = 0; qb2 < 2; ++qb2) {
    f32x4 iv;
#pragma unroll
    for (int r = 0; r < 4; ++r) iv[r] = 1.f / lsum[qb2][r];
#pragma unroll
    for (int jd = 0; jd < 4; ++jd)
#pragma unroll
      for (int r = 0; r < 4; ++r) {
        const size_t row = rb + qb + qb2 * 16 + l4 * 4 + r;
        qkv[row * 3072 + h * 64 + jd * 16 + l15] = (h16)(o[qb2][jd][r] * iv[r]);
      }
  }
#undef ISSUEK2
#undef VLOAD2
#undef VSTOREM2
#undef COMPUTE1
#undef COMPUTE2
#undef ENDBAR
#undef BODYP
}

extern "C" void kernel_launch(void* const* d_in, const int* in_sizes, int n_in,
                              void* d_out, int out_size, void* d_ws, size_t ws_size,
                              hipStream_t stream) {
  const float* x  = (const float*)d_in[0];
  const float* g  = (const float*)d_in[1];
  const float* be = (const float*)d_in[2];
  const float* wq = (const float*)d_in[3];
  const float* wo = (const float*)d_in[4];
  float* out = (float*)d_out;

  char* ws = (char*)d_ws;
  h16* xn   = (h16*)ws;                    // 16 MB [8192,1024]; becomes vT after QKV GEMM
  h16* wqkv = (h16*)(ws + 16777216);       //  6 MB [3072,1024]
  h16* wout = (h16*)(ws + 23068672);       //  2 MB [1024,1024]
  h16* qkv  = (h16*)(ws + 25165824);       // 48 MB [8192,3072] (Q scaled; attn out -> Q cols)
  h16* vT   = xn;                          // 16 MB [64*bh][2048]

  prep_k<<<dim3(8192 + 3072 + 1024), dim3(256), 0, stream>>>(x, g, be, xn, wq, wqkv, wo, wout);
  // Q pre-scale: (1/sqrt(64)) * log2(e) -> softmax runs in exp2 domain
  gemm8<<<dim3(32, 24), dim3(512), 0, stream>>>(xn, 1024, wqkv, (float*)nullptr, qkv,
                                                8192, 3072, 1024, 1024, 0.18033688f);
  vt_k<<<dim3(32, 64), dim3(256), 0, stream>>>(qkv, vT);
  attn_k<<<dim3(64, 8), dim3(512), 0, stream>>>(qkv, vT);
  gemm8<<<dim3(32, 8), dim3(512), 0, stream>>>(qkv, 3072, wout, out, (h16*)nullptr,
                                               8192, 1024, 1024, 0, 1.f);
}

// Round 18
// 174.576 us; speedup vs baseline: 1.0961x; 1.0961x over previous
//
#include <hip/hip_runtime.h>

// Fused LN -> QKV -> MHA -> out-proj for [4,2048,1024], 16 heads, hd=64.
// GEMMs: templated 128xBN tile (BN=192 QKV / 128 out), BK=64, conflict-free
// 8-slot XOR swizzle, 2-buffer single-barrier pipeline, 2 blocks/CU.
// Attention: 8-wave/256-q blocks, paired KV tiles (1 barrier / 128 kv rows),
// swapped QK^T, in-register P (v_cvt_pkrtz packing), no max tracking, MFMA
// ones-column row sums, XCD-grouped grid. LN+weight-cvt merged in one launch.
// [r17 lesson: 256x128/144KB 8-phase port -> 1 block/CU, regressed; reverted]

typedef _Float16 h16;
typedef __attribute__((ext_vector_type(8))) _Float16 h16x8;
typedef __attribute__((ext_vector_type(4))) _Float16 h16x4;
typedef __attribute__((ext_vector_type(2))) _Float16 h16x2;
typedef __attribute__((ext_vector_type(4))) float f32x4;

#define B_ 4
#define S_ 2048
#define D_ 1024

static __device__ __forceinline__ void async16(void* lds, const void* g) {
  __builtin_amdgcn_global_load_lds((const __attribute__((address_space(1))) void*)g,
                                   (__attribute__((address_space(3))) void*)lds,
                                   16, 0, 0);
}

static __device__ __forceinline__ float ex2(float x) {
  float r;
  asm("v_exp_f32 %0, %1" : "=v"(r) : "v"(x));
  return r;
}

static __device__ __forceinline__ h16x2 pk2(float a, float b) {
  h16x2 r;
  asm("v_cvt_pkrtz_f16_f32 %0, %1, %2" : "=v"(r) : "v"(a), "v"(b));
  return r;
}

union U8 { h16x8 v; h16x2 h[4]; };

// ---------------- prep: LN (blocks 0..8191) + weight cvt (rest) -------------
__global__ __launch_bounds__(256) void prep_k(const float* __restrict__ x,
                                              const float* __restrict__ g,
                                              const float* __restrict__ be,
                                              h16* __restrict__ xn,
                                              const float* __restrict__ wq,
                                              h16* __restrict__ wqkv,
                                              const float* __restrict__ wo,
                                              h16* __restrict__ wout) {
  const int bid = blockIdx.x;
  const int tid = threadIdx.x;
  if (bid < 8192) {
    const int row = bid;
    const float4 v = ((const float4*)(x + (size_t)row * D_))[tid];
    float s = v.x + v.y + v.z + v.w;
    float s2 = v.x * v.x + v.y * v.y + v.z * v.z + v.w * v.w;
#pragma unroll
    for (int msk = 1; msk < 64; msk <<= 1) {
      s += __shfl_xor(s, msk);
      s2 += __shfl_xor(s2, msk);
    }
    __shared__ float red[8];
    const int wv = tid >> 6, ln = tid & 63;
    if (ln == 0) { red[wv] = s; red[wv + 4] = s2; }
    __syncthreads();
    s = red[0] + red[1] + red[2] + red[3];
    s2 = red[4] + red[5] + red[6] + red[7];
    const float mu = s * (1.f / D_);
    const float rs = rsqrtf(s2 * (1.f / D_) - mu * mu + 1e-5f);
    const float4 gv = ((const float4*)g)[tid];
    const float4 bv = ((const float4*)be)[tid];
    h16x4 o;
    o[0] = (h16)((v.x - mu) * rs * gv.x + bv.x);
    o[1] = (h16)((v.y - mu) * rs * gv.y + bv.y);
    o[2] = (h16)((v.z - mu) * rs * gv.z + bv.z);
    o[3] = (h16)((v.w - mu) * rs * gv.w + bv.w);
    *(h16x4*)(xn + (size_t)row * D_ + tid * 4) = o;
  } else if (bid < 8192 + 3072) {
    const int i = (bid - 8192) * 256 + tid;
    const float4 v = ((const float4*)wq)[i];
    h16x4 r;
    r[0] = (h16)v.x; r[1] = (h16)v.y; r[2] = (h16)v.z; r[3] = (h16)v.w;
    *(h16x4*)(wqkv + (size_t)i * 4) = r;
  } else {
    const int i = (bid - 8192 - 3072) * 256 + tid;
    const float4 v = ((const float4*)wo)[i];
    h16x4 r;
    r[0] = (h16)v.x; r[1] = (h16)v.y; r[2] = (h16)v.z; r[3] = (h16)v.w;
    *(h16x4*)(wout + (size_t)i * 4) = r;
  }
}

// ---------------- V transpose: qkv V-region -> vT[bh*64+d][2048 kv] ----------
__global__ __launch_bounds__(256) void vt_k(const h16* __restrict__ qkv,
                                            h16* __restrict__ vT) {
  __shared__ h16 T[64 * 72];
  const int tid = threadIdx.x;
  const int kv0 = blockIdx.x * 64;
  const int bh = blockIdx.y;
  const int b = bh >> 4, h = bh & 15;
#pragma unroll
  for (int it = 0; it < 2; ++it) {
    const int s = tid + it * 256;
    const int kv = s >> 3, sl = s & 7;
    const int wsl = sl ^ ((kv >> 3) & 7);
    const h16x8 v = *(const h16x8*)(qkv + (size_t)(b * S_ + kv0 + kv) * 3072 + 2048 + h * 64 + sl * 8);
    *(h16x8*)(T + kv * 72 + wsl * 8) = v;
  }
  __syncthreads();
#pragma unroll
  for (int it = 0; it < 2; ++it) {
    const int s = tid + it * 256;
    const int d = s >> 3, sl = s & 7;
    h16x8 v;
#pragma unroll
    for (int j = 0; j < 8; ++j) {
      const int kv = sl * 8 + j;
      v[j] = T[kv * 72 + (((d >> 3) ^ sl) & 7) * 8 + (d & 7)];
    }
    *(h16x8*)(vT + (size_t)(bh * 64 + d) * 2048 + kv0 + sl * 8) = v;
  }
}

// ---------------- GEMM2: C[M,N] = A[M,K]*B[N,K]^T, 128xBN tile, BK=64 -------
template <int BN>
__global__ __launch_bounds__(256, 2) void gemm2(const h16* __restrict__ A, int lda,
                                                const h16* __restrict__ Bm,
                                                float* __restrict__ Cf,
                                                h16* __restrict__ Ch,
                                                int M, int N, int K,
                                                int scale_cols, float scale) {
  constexpr int NB = BN / 32;
  constexpr int JF = BN / 32;
  __shared__ __align__(16) h16 As[2][128 * 64];
  __shared__ __align__(16) h16 Bs[2][BN * 64];
  const int tid = threadIdx.x;
  const int wv = tid >> 6, ln = tid & 63;
  const int l15 = ln & 15, l4 = ln >> 4;
  const int row0 = blockIdx.x * 128, col0 = blockIdx.y * BN;
  const int wm = (wv >> 1) * 64, wn = (wv & 1) * (BN / 2);
  f32x4 acc[4][JF] = {};

  const int srow = wv * 8 + (ln >> 3);
  const int sslot = (ln & 7) ^ ((ln >> 3) & 7);
  const h16* ag = A + (size_t)(row0 + srow) * lda + sslot * 8;
  const h16* bg = Bm + (size_t)(col0 + srow) * K + sslot * 8;

  auto stage = [&](int buf, int t) {
    const size_t k_ = (size_t)t * 64;
#pragma unroll
    for (int c = 0; c < 4; ++c)
      async16((char*)As[buf] + c * 4096 + wv * 1024, ag + (size_t)(c * 32) * lda + k_);
#pragma unroll
    for (int c = 0; c < NB; ++c)
      async16((char*)Bs[buf] + c * 4096 + wv * 1024, bg + (size_t)(c * 32) * K + k_);
  };

  auto compute = [&](int buf) {
    const h16* Ab_ = As[buf];
    const h16* Bb_ = Bs[buf];
#pragma unroll
    for (int ks = 0; ks < 2; ++ks) {
      h16x8 af[4], bf[JF];
#pragma unroll
      for (int i = 0; i < 4; ++i)
        af[i] = *(const h16x8*)(Ab_ + (wm + i * 16 + l15) * 64 +
                                (((ks * 4 + l4) ^ (l15 & 7)) * 8));
#pragma unroll
      for (int j = 0; j < JF; ++j)
        bf[j] = *(const h16x8*)(Bb_ + (wn + j * 16 + l15) * 64 +
                                (((ks * 4 + l4) ^ (l15 & 7)) * 8));
      __builtin_amdgcn_s_setprio(1);
#pragma unroll
      for (int i = 0; i < 4; ++i)
#pragma unroll
        for (int j = 0; j < JF; ++j)
          acc[i][j] = __builtin_amdgcn_mfma_f32_16x16x32_f16(af[i], bf[j], acc[i][j], 0, 0, 0);
      __builtin_amdgcn_s_setprio(0);
    }
  };

  stage(0, 0);
  for (int t = 0; t < 16; ++t) {
    asm volatile("s_waitcnt vmcnt(0) lgkmcnt(0)" ::: "memory");
    __builtin_amdgcn_sched_barrier(0);
    __builtin_amdgcn_s_barrier();
    __builtin_amdgcn_sched_barrier(0);
    if (t + 1 < 16) stage((t + 1) & 1, t + 1);
    compute(t & 1);
  }

#pragma unroll
  for (int i = 0; i < 4; ++i)
#pragma unroll
    for (int j = 0; j < JF; ++j) {
      const int col = col0 + wn + j * 16 + l15;
      const float sc = (col < scale_cols) ? scale : 1.f;
#pragma unroll
      for (int r = 0; r < 4; ++r) {
        const int row = row0 + wm + i * 16 + l4 * 4 + r;
        const float vv = acc[i][j][r] * sc;
        if (Ch) Ch[(size_t)row * N + col] = (h16)vv;
        else    Cf[(size_t)row * N + col] = vv;
      }
    }
}

// ---------------- Flash attention (8-wave, paired KV tiles) ----------------
__global__ __launch_bounds__(512) void attn_k(h16* __restrict__ qkv,
                                              const h16* __restrict__ vT) {
  __shared__ __align__(16) h16 Ks[2][2][64 * 64];
  __shared__ __align__(16) h16 Vs[2][2][64 * 64];
  const int tid = threadIdx.x;
  const int wv = tid >> 6, ln = tid & 63;
  const int l15 = ln & 15, l4 = ln >> 4;
  const int bh = blockIdx.x;
  const int b = bh >> 4, h = bh & 15;
  const size_t rb = (size_t)b * S_;
  const int qb = blockIdx.y * 256 + wv * 32;

  h16x8 qf[2][2];
#pragma unroll
  for (int qb2 = 0; qb2 < 2; ++qb2)
#pragma unroll
    for (int ks = 0; ks < 2; ++ks)
      qf[qb2][ks] = *(const h16x8*)(qkv + (rb + qb + qb2 * 16 + l15) * 3072 + h * 64 + ks * 32 + l4 * 8);

  f32x4 o[2][4] = {};
  f32x4 lsum[2] = {};
  h16x8 ones8;
#pragma unroll
  for (int j = 0; j < 8; ++j) ones8[j] = (h16)1.f;

  const int srow = wv * 8 + (ln >> 3);
  const int ssl = (ln & 7) ^ (srow & 7);
  const h16* kgb = qkv + (rb + srow) * 3072 + 1024 + h * 64 + ssl * 8;

  const int vd = tid >> 3;
  const int s8 = tid & 7;
  const int vks = s8 >> 2, vb0b = s8 & 1, vhi = (s8 >> 1) & 1;
  const int vd7 = vd & 7;
  const h16* vgb = vT + (size_t)(bh * 64 + vd) * 2048 + s8 * 8;
  const int dstA = vd * 64 + (((vks * 4 + (vb0b * 2)) ^ vd7) * 8) + vhi * 4;
  const int dstB = vd * 64 + (((vks * 4 + (vb0b * 2 + 1)) ^ vd7) * 8) + vhi * 4;

  int jro[4], slx[2];
#pragma unroll
  for (int j = 0; j < 4; ++j) jro[j] = (j * 16 + l15) * 64;
#pragma unroll
  for (int ks = 0; ks < 2; ++ks) slx[ks] = ((ks * 4 + l4) ^ (l15 & 7)) * 8;

  h16x8 va0, va1, vb0, vb1;

#define ISSUEK2(BUF, P) do {                                                 \
    const h16* kg_ = kgb + (size_t)(2 * (P)) * 64 * 3072;                    \
    async16((char*)Ks[BUF][0] + wv * 1024, kg_);                             \
    async16((char*)Ks[BUF][1] + wv * 1024, kg_ + (size_t)64 * 3072);         \
  } while (0)

#define VLOAD2(P, R0, R1) do {                                               \
    R0 = *(const h16x8*)(vgb + (2 * (P)) * 64);                              \
    R1 = *(const h16x8*)(vgb + (2 * (P) + 1) * 64);                          \
  } while (0)

#define VSTOREM2(BUF, S0, S1) do {                                           \
    *(h16x4*)(Vs[BUF][0] + dstA) = __builtin_shufflevector(S0, S0, 0, 1, 2, 3); \
    *(h16x4*)(Vs[BUF][0] + dstB) = __builtin_shufflevector(S0, S0, 4, 5, 6, 7); \
    *(h16x4*)(Vs[BUF][1] + dstA) = __builtin_shufflevector(S1, S1, 0, 1, 2, 3); \
    *(h16x4*)(Vs[BUF][1] + dstB) = __builtin_shufflevector(S1, S1, 4, 5, 6, 7); \
  } while (0)

#define COMPUTE1(Kb_, Vb_) do {                                              \
    f32x4 st[2][4] = {};                                                     \
    __builtin_amdgcn_s_setprio(1);                                           \
    _Pragma("unroll")                                                        \
    for (int ks = 0; ks < 2; ++ks) {                                         \
      h16x8 kb[4];                                                           \
      _Pragma("unroll")                                                      \
      for (int jb = 0; jb < 4; ++jb)                                         \
        kb[jb] = *(const h16x8*)(Kb_ + jro[jb] + slx[ks]);                   \
      _Pragma("unroll")                                                      \
      for (int qq = 0; qq < 2; ++qq)                                         \
        _Pragma("unroll")                                                    \
        for (int jb = 0; jb < 4; ++jb)                                       \
          st[qq][jb] = __builtin_amdgcn_mfma_f32_16x16x32_f16(kb[jb], qf[qq][ks], st[qq][jb], 0, 0, 0); \
    }                                                                        \
    __builtin_amdgcn_s_setprio(0);                                           \
    h16x8 vfr[2][4];                                                         \
    _Pragma("unroll")                                                        \
    for (int ks = 0; ks < 2; ++ks)                                           \
      _Pragma("unroll")                                                      \
      for (int jd = 0; jd < 4; ++jd)                                         \
        vfr[ks][jd] = *(const h16x8*)(Vb_ + jro[jd] + slx[ks]);              \
    _Pragma("unroll")                                                        \
    for (int qq = 0; qq < 2; ++qq) {                                         \
      h16x8 pa[2];                                                           \
      _Pragma("unroll")                                                      \
      for (int ks = 0; ks < 2; ++ks) {                                       \
        U8 u_;                                                               \
        u_.h[0] = pk2(ex2(st[qq][2 * ks][0]), ex2(st[qq][2 * ks][1]));       \
        u_.h[1] = pk2(ex2(st[qq][2 * ks][2]), ex2(st[qq][2 * ks][3]));       \
        u_.h[2] = pk2(ex2(st[qq][2 * ks + 1][0]), ex2(st[qq][2 * ks + 1][1])); \
        u_.h[3] = pk2(ex2(st[qq][2 * ks + 1][2]), ex2(st[qq][2 * ks + 1][3])); \
        pa[ks] = u_.v;                                                       \
      }                                                                      \
      __builtin_amdgcn_s_setprio(1);                                         \
      _Pragma("unroll")                                                      \
      for (int jd = 0; jd < 4; ++jd)                                         \
        o[qq][jd] = __builtin_amdgcn_mfma_f32_16x16x32_f16(pa[0], vfr[0][jd], o[qq][jd], 0, 0, 0); \
      lsum[qq] = __builtin_amdgcn_mfma_f32_16x16x32_f16(pa[0], ones8, lsum[qq], 0, 0, 0); \
      _Pragma("unroll")                                                      \
      for (int jd = 0; jd < 4; ++jd)                                         \
        o[qq][jd] = __builtin_amdgcn_mfma_f32_16x16x32_f16(pa[1], vfr[1][jd], o[qq][jd], 0, 0, 0); \
      lsum[qq] = __builtin_amdgcn_mfma_f32_16x16x32_f16(pa[1], ones8, lsum[qq], 0, 0, 0); \
      __builtin_amdgcn_s_setprio(0);                                         \
    }                                                                        \
  } while (0)

#define COMPUTE2(BUF) do {                                                   \
    COMPUTE1((Ks[BUF][0]), (Vs[BUF][0]));                                    \
    COMPUTE1((Ks[BUF][1]), (Vs[BUF][1]));                                    \
  } while (0)

#define ENDBAR(VM) do {                                                      \
    asm volatile("s_waitcnt vmcnt(" #VM ") lgkmcnt(0)" ::: "memory");        \
    __builtin_amdgcn_sched_barrier(0);                                       \
    __builtin_amdgcn_s_barrier();                                            \
  } while (0)

#define BODYP(P, VM, VS0, VS1, VL0, VL1) do {                                \
    VSTOREM2(((P) + 1) & 1, VS0, VS1);                                       \
    ISSUEK2(((P) + 1) & 1, (P) + 1);                                         \
    if ((P) + 2 < 16) VLOAD2((P) + 2, VL0, VL1);                             \
    COMPUTE2((P) & 1);                                                       \
    ENDBAR(VM);                                                              \
  } while (0)

  ISSUEK2(0, 0);
  VLOAD2(0, va0, va1);
  VSTOREM2(0, va0, va1);
  VLOAD2(1, vb0, vb1);
  ENDBAR(2);

  for (int p = 0; p < 14; p += 2) {
    BODYP(p + 0, 2, vb0, vb1, va0, va1);
    BODYP(p + 1, 2, va0, va1, vb0, vb1);
  }
  BODYP(14, 0, vb0, vb1, va0, va1);
  COMPUTE2(1);

#pragma unroll
  for (int qb2 = 0; qb2 < 2; ++qb2) {
    f32x4 iv;
#pragma unroll
    for (int r = 0; r < 4; ++r) iv[r] = 1.f / lsum[qb2][r];
#pragma unroll
    for (int jd = 0; jd < 4; ++jd)
#pragma unroll
      for (int r = 0; r < 4; ++r) {
        const size_t row = rb + qb + qb2 * 16 + l4 * 4 + r;
        qkv[row * 3072 + h * 64 + jd * 16 + l15] = (h16)(o[qb2][jd][r] * iv[r]);
      }
  }
#undef ISSUEK2
#undef VLOAD2
#undef VSTOREM2
#undef COMPUTE1
#undef COMPUTE2
#undef ENDBAR
#undef BODYP
}

extern "C" void kernel_launch(void* const* d_in, const int* in_sizes, int n_in,
                              void* d_out, int out_size, void* d_ws, size_t ws_size,
                              hipStream_t stream) {
  const float* x  = (const float*)d_in[0];
  const float* g  = (const float*)d_in[1];
  const float* be = (const float*)d_in[2];
  const float* wq = (const float*)d_in[3];
  const float* wo = (const float*)d_in[4];
  float* out = (float*)d_out;

  char* ws = (char*)d_ws;
  h16* xn   = (h16*)ws;                    // 16 MB [8192,1024]; becomes vT after QKV GEMM
  h16* wqkv = (h16*)(ws + 16777216);       //  6 MB [3072,1024]
  h16* wout = (h16*)(ws + 23068672);       //  2 MB [1024,1024]
  h16* qkv  = (h16*)(ws + 25165824);       // 48 MB [8192,3072] (Q scaled; attn out -> Q cols)
  h16* vT   = xn;                          // 16 MB [64*bh][2048]

  prep_k<<<dim3(8192 + 3072 + 1024), dim3(256), 0, stream>>>(x, g, be, xn, wq, wqkv, wo, wout);
  // Q pre-scale: (1/sqrt(64)) * log2(e) -> softmax runs in exp2 domain
  gemm2<192><<<dim3(64, 16), dim3(256), 0, stream>>>(xn, 1024, wqkv, (float*)nullptr, qkv,
                                                     8192, 3072, 1024, 1024, 0.18033688f);
  vt_k<<<dim3(32, 64), dim3(256), 0, stream>>>(qkv, vT);
  attn_k<<<dim3(64, 8), dim3(512), 0, stream>>>(qkv, vT);
  gemm2<128><<<dim3(64, 8), dim3(256), 0, stream>>>(qkv, 3072, wout, out, (h16*)nullptr,
                                                    8192, 1024, 1024, 0, 1.f);
}

// Round 20
// 173.626 us; speedup vs baseline: 1.1021x; 1.0055x over previous
//
#include <hip/hip_runtime.h>

// Fused LN -> QKV -> MHA -> out-proj for [4,2048,1024], 16 heads, hd=64.
// GEMMs: templated 128xBN tile (BN=192 QKV / 128 out), BK=64, conflict-free
// 8-slot XOR swizzle, 2-buffer single-barrier pipeline, 2 blocks/CU.
// Attention: 8-wave/256-q blocks, paired KV tiles (1 barrier / 128 kv rows),
// swapped QK^T, in-register P (v_cvt_pkrtz packing), no max tracking, MFMA
// ones-column row sums, XCD-grouped grid. LN+weight-cvt merged in one launch.
// [r17: 8-phase port regressed (1 block/CU). r19: 32x32 MFMA port failed
//  validation (operand-layout assumption wrong). This is the verified best.]

typedef _Float16 h16;
typedef __attribute__((ext_vector_type(8))) _Float16 h16x8;
typedef __attribute__((ext_vector_type(4))) _Float16 h16x4;
typedef __attribute__((ext_vector_type(2))) _Float16 h16x2;
typedef __attribute__((ext_vector_type(4))) float f32x4;

#define B_ 4
#define S_ 2048
#define D_ 1024

static __device__ __forceinline__ void async16(void* lds, const void* g) {
  __builtin_amdgcn_global_load_lds((const __attribute__((address_space(1))) void*)g,
                                   (__attribute__((address_space(3))) void*)lds,
                                   16, 0, 0);
}

static __device__ __forceinline__ float ex2(float x) {
  float r;
  asm("v_exp_f32 %0, %1" : "=v"(r) : "v"(x));
  return r;
}

static __device__ __forceinline__ h16x2 pk2(float a, float b) {
  h16x2 r;
  asm("v_cvt_pkrtz_f16_f32 %0, %1, %2" : "=v"(r) : "v"(a), "v"(b));
  return r;
}

union U8 { h16x8 v; h16x2 h[4]; };

// ---------------- prep: LN (blocks 0..8191) + weight cvt (rest) -------------
__global__ __launch_bounds__(256) void prep_k(const float* __restrict__ x,
                                              const float* __restrict__ g,
                                              const float* __restrict__ be,
                                              h16* __restrict__ xn,
                                              const float* __restrict__ wq,
                                              h16* __restrict__ wqkv,
                                              const float* __restrict__ wo,
                                              h16* __restrict__ wout) {
  const int bid = blockIdx.x;
  const int tid = threadIdx.x;
  if (bid < 8192) {
    const int row = bid;
    const float4 v = ((const float4*)(x + (size_t)row * D_))[tid];
    float s = v.x + v.y + v.z + v.w;
    float s2 = v.x * v.x + v.y * v.y + v.z * v.z + v.w * v.w;
#pragma unroll
    for (int msk = 1; msk < 64; msk <<= 1) {
      s += __shfl_xor(s, msk);
      s2 += __shfl_xor(s2, msk);
    }
    __shared__ float red[8];
    const int wv = tid >> 6, ln = tid & 63;
    if (ln == 0) { red[wv] = s; red[wv + 4] = s2; }
    __syncthreads();
    s = red[0] + red[1] + red[2] + red[3];
    s2 = red[4] + red[5] + red[6] + red[7];
    const float mu = s * (1.f / D_);
    const float rs = rsqrtf(s2 * (1.f / D_) - mu * mu + 1e-5f);
    const float4 gv = ((const float4*)g)[tid];
    const float4 bv = ((const float4*)be)[tid];
    h16x4 o;
    o[0] = (h16)((v.x - mu) * rs * gv.x + bv.x);
    o[1] = (h16)((v.y - mu) * rs * gv.y + bv.y);
    o[2] = (h16)((v.z - mu) * rs * gv.z + bv.z);
    o[3] = (h16)((v.w - mu) * rs * gv.w + bv.w);
    *(h16x4*)(xn + (size_t)row * D_ + tid * 4) = o;
  } else if (bid < 8192 + 3072) {
    const int i = (bid - 8192) * 256 + tid;
    const float4 v = ((const float4*)wq)[i];
    h16x4 r;
    r[0] = (h16)v.x; r[1] = (h16)v.y; r[2] = (h16)v.z; r[3] = (h16)v.w;
    *(h16x4*)(wqkv + (size_t)i * 4) = r;
  } else {
    const int i = (bid - 8192 - 3072) * 256 + tid;
    const float4 v = ((const float4*)wo)[i];
    h16x4 r;
    r[0] = (h16)v.x; r[1] = (h16)v.y; r[2] = (h16)v.z; r[3] = (h16)v.w;
    *(h16x4*)(wout + (size_t)i * 4) = r;
  }
}

// ---------------- V transpose: qkv V-region -> vT[bh*64+d][2048 kv] ----------
__global__ __launch_bounds__(256) void vt_k(const h16* __restrict__ qkv,
                                            h16* __restrict__ vT) {
  __shared__ h16 T[64 * 72];
  const int tid = threadIdx.x;
  const int kv0 = blockIdx.x * 64;
  const int bh = blockIdx.y;
  const int b = bh >> 4, h = bh & 15;
#pragma unroll
  for (int it = 0; it < 2; ++it) {
    const int s = tid + it * 256;
    const int kv = s >> 3, sl = s & 7;
    const int wsl = sl ^ ((kv >> 3) & 7);
    const h16x8 v = *(const h16x8*)(qkv + (size_t)(b * S_ + kv0 + kv) * 3072 + 2048 + h * 64 + sl * 8);
    *(h16x8*)(T + kv * 72 + wsl * 8) = v;
  }
  __syncthreads();
#pragma unroll
  for (int it = 0; it < 2; ++it) {
    const int s = tid + it * 256;
    const int d = s >> 3, sl = s & 7;
    h16x8 v;
#pragma unroll
    for (int j = 0; j < 8; ++j) {
      const int kv = sl * 8 + j;
      v[j] = T[kv * 72 + (((d >> 3) ^ sl) & 7) * 8 + (d & 7)];
    }
    *(h16x8*)(vT + (size_t)(bh * 64 + d) * 2048 + kv0 + sl * 8) = v;
  }
}

// ---------------- GEMM2: C[M,N] = A[M,K]*B[N,K]^T, 128xBN tile, BK=64 -------
template <int BN>
__global__ __launch_bounds__(256, 2) void gemm2(const h16* __restrict__ A, int lda,
                                                const h16* __restrict__ Bm,
                                                float* __restrict__ Cf,
                                                h16* __restrict__ Ch,
                                                int M, int N, int K,
                                                int scale_cols, float scale) {
  constexpr int NB = BN / 32;
  constexpr int JF = BN / 32;
  __shared__ __align__(16) h16 As[2][128 * 64];
  __shared__ __align__(16) h16 Bs[2][BN * 64];
  const int tid = threadIdx.x;
  const int wv = tid >> 6, ln = tid & 63;
  const int l15 = ln & 15, l4 = ln >> 4;
  const int row0 = blockIdx.x * 128, col0 = blockIdx.y * BN;
  const int wm = (wv >> 1) * 64, wn = (wv & 1) * (BN / 2);
  f32x4 acc[4][JF] = {};

  const int srow = wv * 8 + (ln >> 3);
  const int sslot = (ln & 7) ^ ((ln >> 3) & 7);
  const h16* ag = A + (size_t)(row0 + srow) * lda + sslot * 8;
  const h16* bg = Bm + (size_t)(col0 + srow) * K + sslot * 8;

  auto stage = [&](int buf, int t) {
    const size_t k_ = (size_t)t * 64;
#pragma unroll
    for (int c = 0; c < 4; ++c)
      async16((char*)As[buf] + c * 4096 + wv * 1024, ag + (size_t)(c * 32) * lda + k_);
#pragma unroll
    for (int c = 0; c < NB; ++c)
      async16((char*)Bs[buf] + c * 4096 + wv * 1024, bg + (size_t)(c * 32) * K + k_);
  };

  auto compute = [&](int buf) {
    const h16* Ab_ = As[buf];
    const h16* Bb_ = Bs[buf];
#pragma unroll
    for (int ks = 0; ks < 2; ++ks) {
      h16x8 af[4], bf[JF];
#pragma unroll
      for (int i = 0; i < 4; ++i)
        af[i] = *(const h16x8*)(Ab_ + (wm + i * 16 + l15) * 64 +
                                (((ks * 4 + l4) ^ (l15 & 7)) * 8));
#pragma unroll
      for (int j = 0; j < JF; ++j)
        bf[j] = *(const h16x8*)(Bb_ + (wn + j * 16 + l15) * 64 +
                                (((ks * 4 + l4) ^ (l15 & 7)) * 8));
      __builtin_amdgcn_s_setprio(1);
#pragma unroll
      for (int i = 0; i < 4; ++i)
#pragma unroll
        for (int j = 0; j < JF; ++j)
          acc[i][j] = __builtin_amdgcn_mfma_f32_16x16x32_f16(af[i], bf[j], acc[i][j], 0, 0, 0);
      __builtin_amdgcn_s_setprio(0);
    }
  };

  stage(0, 0);
  for (int t = 0; t < 16; ++t) {
    asm volatile("s_waitcnt vmcnt(0) lgkmcnt(0)" ::: "memory");
    __builtin_amdgcn_sched_barrier(0);
    __builtin_amdgcn_s_barrier();
    __builtin_amdgcn_sched_barrier(0);
    if (t + 1 < 16) stage((t + 1) & 1, t + 1);
    compute(t & 1);
  }

#pragma unroll
  for (int i = 0; i < 4; ++i)
#pragma unroll
    for (int j = 0; j < JF; ++j) {
      const int col = col0 + wn + j * 16 + l15;
      const float sc = (col < scale_cols) ? scale : 1.f;
#pragma unroll
      for (int r = 0; r < 4; ++r) {
        const int row = row0 + wm + i * 16 + l4 * 4 + r;
        const float vv = acc[i][j][r] * sc;
        if (Ch) Ch[(size_t)row * N + col] = (h16)vv;
        else    Cf[(size_t)row * N + col] = vv;
      }
    }
}

// ---------------- Flash attention (8-wave, paired KV tiles) ----------------
__global__ __launch_bounds__(512) void attn_k(h16* __restrict__ qkv,
                                              const h16* __restrict__ vT) {
  __shared__ __align__(16) h16 Ks[2][2][64 * 64];
  __shared__ __align__(16) h16 Vs[2][2][64 * 64];
  const int tid = threadIdx.x;
  const int wv = tid >> 6, ln = tid & 63;
  const int l15 = ln & 15, l4 = ln >> 4;
  const int bh = blockIdx.x;
  const int b = bh >> 4, h = bh & 15;
  const size_t rb = (size_t)b * S_;
  const int qb = blockIdx.y * 256 + wv * 32;

  h16x8 qf[2][2];
#pragma unroll
  for (int qb2 = 0; qb2 < 2; ++qb2)
#pragma unroll
    for (int ks = 0; ks < 2; ++ks)
      qf[qb2][ks] = *(const h16x8*)(qkv + (rb + qb + qb2 * 16 + l15) * 3072 + h * 64 + ks * 32 + l4 * 8);

  f32x4 o[2][4] = {};
  f32x4 lsum[2] = {};
  h16x8 ones8;
#pragma unroll
  for (int j = 0; j < 8; ++j) ones8[j] = (h16)1.f;

  const int srow = wv * 8 + (ln >> 3);
  const int ssl = (ln & 7) ^ (srow & 7);
  const h16* kgb = qkv + (rb + srow) * 3072 + 1024 + h * 64 + ssl * 8;

  const int vd = tid >> 3;
  const int s8 = tid & 7;
  const int vks = s8 >> 2, vb0b = s8 & 1, vhi = (s8 >> 1) & 1;
  const int vd7 = vd & 7;
  const h16* vgb = vT + (size_t)(bh * 64 + vd) * 2048 + s8 * 8;
  const int dstA = vd * 64 + (((vks * 4 + (vb0b * 2)) ^ vd7) * 8) + vhi * 4;
  const int dstB = vd * 64 + (((vks * 4 + (vb0b * 2 + 1)) ^ vd7) * 8) + vhi * 4;

  int jro[4], slx[2];
#pragma unroll
  for (int j = 0; j < 4; ++j) jro[j] = (j * 16 + l15) * 64;
#pragma unroll
  for (int ks = 0; ks < 2; ++ks) slx[ks] = ((ks * 4 + l4) ^ (l15 & 7)) * 8;

  h16x8 va0, va1, vb0, vb1;

#define ISSUEK2(BUF, P) do {                                                 \
    const h16* kg_ = kgb + (size_t)(2 * (P)) * 64 * 3072;                    \
    async16((char*)Ks[BUF][0] + wv * 1024, kg_);                             \
    async16((char*)Ks[BUF][1] + wv * 1024, kg_ + (size_t)64 * 3072);         \
  } while (0)

#define VLOAD2(P, R0, R1) do {                                               \
    R0 = *(const h16x8*)(vgb + (2 * (P)) * 64);                              \
    R1 = *(const h16x8*)(vgb + (2 * (P) + 1) * 64);                          \
  } while (0)

#define VSTOREM2(BUF, S0, S1) do {                                           \
    *(h16x4*)(Vs[BUF][0] + dstA) = __builtin_shufflevector(S0, S0, 0, 1, 2, 3); \
    *(h16x4*)(Vs[BUF][0] + dstB) = __builtin_shufflevector(S0, S0, 4, 5, 6, 7); \
    *(h16x4*)(Vs[BUF][1] + dstA) = __builtin_shufflevector(S1, S1, 0, 1, 2, 3); \
    *(h16x4*)(Vs[BUF][1] + dstB) = __builtin_shufflevector(S1, S1, 4, 5, 6, 7); \
  } while (0)

#define COMPUTE1(Kb_, Vb_) do {                                              \
    f32x4 st[2][4] = {};                                                     \
    __builtin_amdgcn_s_setprio(1);                                           \
    _Pragma("unroll")                                                        \
    for (int ks = 0; ks < 2; ++ks) {                                         \
      h16x8 kb[4];                                                           \
      _Pragma("unroll")                                                      \
      for (int jb = 0; jb < 4; ++jb)                                         \
        kb[jb] = *(const h16x8*)(Kb_ + jro[jb] + slx[ks]);                   \
      _Pragma("unroll")                                                      \
      for (int qq = 0; qq < 2; ++qq)                                         \
        _Pragma("unroll")                                                    \
        for (int jb = 0; jb < 4; ++jb)                                       \
          st[qq][jb] = __builtin_amdgcn_mfma_f32_16x16x32_f16(kb[jb], qf[qq][ks], st[qq][jb], 0, 0, 0); \
    }                                                                        \
    __builtin_amdgcn_s_setprio(0);                                           \
    h16x8 vfr[2][4];                                                         \
    _Pragma("unroll")                                                        \
    for (int ks = 0; ks < 2; ++ks)                                           \
      _Pragma("unroll")                                                      \
      for (int jd = 0; jd < 4; ++jd)                                         \
        vfr[ks][jd] = *(const h16x8*)(Vb_ + jro[jd] + slx[ks]);              \
    _Pragma("unroll")                                                        \
    for (int qq = 0; qq < 2; ++qq) {                                         \
      h16x8 pa[2];                                                           \
      _Pragma("unroll")                                                      \
      for (int ks = 0; ks < 2; ++ks) {                                       \
        U8 u_;                                                               \
        u_.h[0] = pk2(ex2(st[qq][2 * ks][0]), ex2(st[qq][2 * ks][1]));       \
        u_.h[1] = pk2(ex2(st[qq][2 * ks][2]), ex2(st[qq][2 * ks][3]));       \
        u_.h[2] = pk2(ex2(st[qq][2 * ks + 1][0]), ex2(st[qq][2 * ks + 1][1])); \
        u_.h[3] = pk2(ex2(st[qq][2 * ks + 1][2]), ex2(st[qq][2 * ks + 1][3])); \
        pa[ks] = u_.v;                                                       \
      }                                                                      \
      __builtin_amdgcn_s_setprio(1);                                         \
      _Pragma("unroll")                                                      \
      for (int jd = 0; jd < 4; ++jd)                                         \
        o[qq][jd] = __builtin_amdgcn_mfma_f32_16x16x32_f16(pa[0], vfr[0][jd], o[qq][jd], 0, 0, 0); \
      lsum[qq] = __builtin_amdgcn_mfma_f32_16x16x32_f16(pa[0], ones8, lsum[qq], 0, 0, 0); \
      _Pragma("unroll")                                                      \
      for (int jd = 0; jd < 4; ++jd)                                         \
        o[qq][jd] = __builtin_amdgcn_mfma_f32_16x16x32_f16(pa[1], vfr[1][jd], o[qq][jd], 0, 0, 0); \
      lsum[qq] = __builtin_amdgcn_mfma_f32_16x16x32_f16(pa[1], ones8, lsum[qq], 0, 0, 0); \
      __builtin_amdgcn_s_setprio(0);                                         \
    }                                                                        \
  } while (0)

#define COMPUTE2(BUF) do {                                                   \
    COMPUTE1((Ks[BUF][0]), (Vs[BUF][0]));                                    \
    COMPUTE1((Ks[BUF][1]), (Vs[BUF][1]));                                    \
  } while (0)

#define ENDBAR(VM) do {                                                      \
    asm volatile("s_waitcnt vmcnt(" #VM ") lgkmcnt(0)" ::: "memory");        \
    __builtin_amdgcn_sched_barrier(0);                                       \
    __builtin_amdgcn_s_barrier();                                            \
  } while (0)

#define BODYP(P, VM, VS0, VS1, VL0, VL1) do {                                \
    VSTOREM2(((P) + 1) & 1, VS0, VS1);                                       \
    ISSUEK2(((P) + 1) & 1, (P) + 1);                                         \
    if ((P) + 2 < 16) VLOAD2((P) + 2, VL0, VL1);                             \
    COMPUTE2((P) & 1);                                                       \
    ENDBAR(VM);                                                              \
  } while (0)

  ISSUEK2(0, 0);
  VLOAD2(0, va0, va1);
  VSTOREM2(0, va0, va1);
  VLOAD2(1, vb0, vb1);
  ENDBAR(2);

  for (int p = 0; p < 14; p += 2) {
    BODYP(p + 0, 2, vb0, vb1, va0, va1);
    BODYP(p + 1, 2, va0, va1, vb0, vb1);
  }
  BODYP(14, 0, vb0, vb1, va0, va1);
  COMPUTE2(1);

#pragma unroll
  for (int qb2 = 0; qb2 < 2; ++qb2) {
    f32x4 iv;
#pragma unroll
    for (int r = 0; r < 4; ++r) iv[r] = 1.f / lsum[qb2][r];
#pragma unroll
    for (int jd = 0; jd < 4; ++jd)
#pragma unroll
      for (int r = 0; r < 4; ++r) {
        const size_t row = rb + qb + qb2 * 16 + l4 * 4 + r;
        qkv[row * 3072 + h * 64 + jd * 16 + l15] = (h16)(o[qb2][jd][r] * iv[r]);
      }
  }
#undef ISSUEK2
#undef VLOAD2
#undef VSTOREM2
#undef COMPUTE1
#undef COMPUTE2
#undef ENDBAR
#undef BODYP
}

extern "C" void kernel_launch(void* const* d_in, const int* in_sizes, int n_in,
                              void* d_out, int out_size, void* d_ws, size_t ws_size,
                              hipStream_t stream) {
  const float* x  = (const float*)d_in[0];
  const float* g  = (const float*)d_in[1];
  const float* be = (const float*)d_in[2];
  const float* wq = (const float*)d_in[3];
  const float* wo = (const float*)d_in[4];
  float* out = (float*)d_out;

  char* ws = (char*)d_ws;
  h16* xn   = (h16*)ws;                    // 16 MB [8192,1024]; becomes vT after QKV GEMM
  h16* wqkv = (h16*)(ws + 16777216);       //  6 MB [3072,1024]
  h16* wout = (h16*)(ws + 23068672);       //  2 MB [1024,1024]
  h16* qkv  = (h16*)(ws + 25165824);       // 48 MB [8192,3072] (Q scaled; attn out -> Q cols)
  h16* vT   = xn;                          // 16 MB [64*bh][2048]

  prep_k<<<dim3(8192 + 3072 + 1024), dim3(256), 0, stream>>>(x, g, be, xn, wq, wqkv, wo, wout);
  // Q pre-scale: (1/sqrt(64)) * log2(e) -> softmax runs in exp2 domain
  gemm2<192><<<dim3(64, 16), dim3(256), 0, stream>>>(xn, 1024, wqkv, (float*)nullptr, qkv,
                                                     8192, 3072, 1024, 1024, 0.18033688f);
  vt_k<<<dim3(32, 64), dim3(256), 0, stream>>>(qkv, vT);
  attn_k<<<dim3(64, 8), dim3(512), 0, stream>>>(qkv, vT);
  gemm2<128><<<dim3(64, 8), dim3(256), 0, stream>>>(qkv, 3072, wout, out, (h16*)nullptr,
                                                    8192, 1024, 1024, 0, 1.f);
}